// Round 9
// baseline (18675.769 us; speedup 1.0000x reference)
//
#include <hip/hip_runtime.h>
#include <hip/hip_bf16.h>
#include <stdint.h>
#include <stddef.h>

// Problem constants
#define B_ 4096
#define S_ 64
#define D_ 512
#define DEPTH_ 4

typedef __attribute__((ext_vector_type(8))) __bf16 bf16x8;
typedef __attribute__((ext_vector_type(4))) float f32x4;
typedef __hip_bfloat16 bf16_t;

// ---------------------------------------------------------------------------
// async global->LDS, 16B per lane. LDS dest is wave-uniform base + lane*16.
// ---------------------------------------------------------------------------
__device__ __forceinline__ void async_copy16(const void* g, void* lds) {
  __builtin_amdgcn_global_load_lds(
      (const __attribute__((address_space(1))) void*)g,
      (__attribute__((address_space(3))) void*)lds, 16, 0, 0);
}

__device__ __forceinline__ float bf2f(bf16_t h) { return __bfloat162float(h); }

// ---------------------------------------------------------------------------
// GEMM: C(M,N) = A(M,K) @ Bt(N,K)^T  (+bias)
//   A, Bt bf16 row-major (K contiguous). fp32 accumulate in AGPRs.
//   EPI 0: X[row*N+col] += acc + bias          (fp32 residual RMW; SPLITK==1)
//   EPI 1: O[row*N+col]  = bf16(relu(acc+b))   (SPLITK==1)
//   EPI 2: O[z*M*N + row*N+col] = bf16(acc (+bias if z==0))  (partials,
//          plain bf16 stores — NO atomics; reduction folded into the next
//          LN-ish kernel which reads X anyway).
// Block: 256 threads = 4 waves in 2x2, wave tile (TM/2)x(TN/2),
// mfma_f32_16x16x32_bf16, m97-style 2-barrier K loop.
// BK=128 (R9): K-loop iters halved vs BK=64 -> half the vmcnt(0)+barrier
// drains. m132's BK=128 occupancy regression can't apply: grids are 512
// blocks = 2/CU, and 64 KB LDS still allows 2/CU (160/64).
// Grid-size rule (R2/R3/R5/R6): keep >=512 blocks (2 blocks/CU).
// XCD swizzle (R8, ~neutral but kept): pin col/K-slices to XCDs.
// ---------------------------------------------------------------------------
template<int TM, int TN, int BK, int EPI, int SPLITK>
__launch_bounds__(256)
__global__ void gemm_bf16(const bf16_t* __restrict__ A,
                          const bf16_t* __restrict__ Bt,
                          const float* __restrict__ bias,
                          float* __restrict__ X,
                          bf16_t* __restrict__ O,
                          int M, int N, int K)
{
  constexpr int WM  = TM / 2, WN = TN / 2;
  constexpr int NMI = WM / 16, NNI = WN / 16;
  constexpr int CA  = TM * BK / 512;   // 1KB staging chunks
  constexpr int CB  = TN * BK / 512;
  constexpr int LPR = BK / 8;          // lanes per row (16B each)
  constexpr int RPC = 512 / BK;        // rows per 1KB chunk

  __shared__ __align__(16) bf16_t sA[TM * BK];
  __shared__ __align__(16) bf16_t sB[TN * BK];

  const int tid  = threadIdx.x;
  const int lane = tid & 63;
  const int wave = tid >> 6;
  const int wm   = wave & 1;
  const int wn   = wave >> 1;

  // XCD-aware remap: pin each col-slice c=(by,bz) to one XCD.
  int bx = blockIdx.x, by = blockIdx.y, bz = blockIdx.z;
  {
    const int lin = blockIdx.x + gridDim.x * (blockIdx.y + gridDim.y * blockIdx.z);
    const int ncs = gridDim.y * gridDim.z;        // col/K slices (8 or 16)
    if (ncs == 8 || ncs == 16) {
      const int cpx = ncs >> 3;                   // slices per XCD (1 or 2)
      const int c   = (lin & 7) * cpx + ((lin >> 3) & (cpx - 1));
      bx = lin / ncs;
      by = c % gridDim.y;
      bz = c / gridDim.y;
    }
  }
  const int m0   = bx * TM;
  const int n0   = by * TN;
  const int KS   = K / SPLITK;
  const int kbeg = bz * KS;

  const int lr = lane / LPR;           // row within chunk
  const int lc = (lane % LPR) * 8;     // bf16 col within row

  f32x4 acc[NMI][NNI];
#pragma unroll
  for (int mi = 0; mi < NMI; ++mi)
#pragma unroll
    for (int ni = 0; ni < NNI; ++ni)
      acc[mi][ni] = (f32x4){0.f, 0.f, 0.f, 0.f};

  for (int k0 = kbeg; k0 < kbeg + KS; k0 += BK) {
#pragma unroll
    for (int c = wave; c < CA; c += 4) {
      const bf16_t* g = A + (size_t)(m0 + c * RPC + lr) * K + (k0 + lc);
      async_copy16(g, (char*)sA + c * 1024);
    }
#pragma unroll
    for (int c = wave; c < CB; c += 4) {
      const bf16_t* g = Bt + (size_t)(n0 + c * RPC + lr) * K + (k0 + lc);
      async_copy16(g, (char*)sB + c * 1024);
    }
    __syncthreads();   // drains vmcnt(0) -> LDS ready

#pragma unroll
    for (int kk = 0; kk < BK; kk += 32) {
      bf16x8 af[NMI], bfv[NNI];
#pragma unroll
      for (int mi = 0; mi < NMI; ++mi)
        af[mi] = *(const bf16x8*)&sA[(wm * WM + mi * 16 + (lane & 15)) * BK + kk + (lane >> 4) * 8];
#pragma unroll
      for (int ni = 0; ni < NNI; ++ni)
        bfv[ni] = *(const bf16x8*)&sB[(wn * WN + ni * 16 + (lane & 15)) * BK + kk + (lane >> 4) * 8];
#pragma unroll
      for (int mi = 0; mi < NMI; ++mi)
#pragma unroll
        for (int ni = 0; ni < NNI; ++ni)
          acc[mi][ni] = __builtin_amdgcn_mfma_f32_16x16x32_bf16(af[mi], bfv[ni], acc[mi][ni], 0, 0, 0);
    }
    __syncthreads();   // protect LDS before next stage
  }

  // epilogue. C/D layout (verified m89/m91): col = lane&15, row = (lane>>4)*4 + r
#pragma unroll
  for (int mi = 0; mi < NMI; ++mi) {
#pragma unroll
    for (int ni = 0; ni < NNI; ++ni) {
      const int col  = n0 + wn * WN + ni * 16 + (lane & 15);
      const int row0 = m0 + wm * WM + mi * 16 + ((lane >> 4) << 2);
      const float bv = (SPLITK == 1 || bz == 0) ? bias[col] : 0.f;
#pragma unroll
      for (int r = 0; r < 4; ++r) {
        const float v = acc[mi][ni][r] + bv;
        const size_t idx = (size_t)(row0 + r) * N + col;
        if constexpr (EPI == 0) {
          X[idx] += v;
        } else if constexpr (EPI == 1) {
          O[idx] = __float2bfloat16(v > 0.f ? v : 0.f);
        } else {
          O[(size_t)bz * M * N + idx] = __float2bfloat16(v);
        }
      }
    }
  }
}

// ---------------------------------------------------------------------------
// LayerNorm row helper: v[8] per lane (64 lanes x 8 = 512), write bf16 row
// ---------------------------------------------------------------------------
__device__ __forceinline__ void ln_store(const float v[8],
                                         const float* __restrict__ gamma,
                                         const float* __restrict__ beta,
                                         bf16_t* __restrict__ yrow, int lane)
{
  float s = 0.f, ss = 0.f;
#pragma unroll
  for (int i = 0; i < 8; ++i) { s += v[i]; ss += v[i] * v[i]; }
#pragma unroll
  for (int o = 32; o; o >>= 1) { s += __shfl_xor(s, o); ss += __shfl_xor(ss, o); }
  const float m   = s * (1.f / D_);
  const float inv = rsqrtf(ss * (1.f / D_) - m * m + 1e-5f);
  const int c0 = lane * 8;
  float g[8], b[8];
  *(float4*)&g[0] = *(const float4*)&gamma[c0];
  *(float4*)&g[4] = *(const float4*)&gamma[c0 + 4];
  *(float4*)&b[0] = *(const float4*)&beta[c0];
  *(float4*)&b[4] = *(const float4*)&beta[c0 + 4];
  alignas(16) bf16_t o8[8];
#pragma unroll
  for (int i = 0; i < 8; ++i)
    o8[i] = __float2bfloat16((v[i] - m) * inv * g[i] + b[i]);
  *(uint4*)&yrow[c0] = *(const uint4*)o8;
}

// fold bf16 partial row-chunk into v[8]
__device__ __forceinline__ void fold_p(float v[8], const bf16_t* pz)
{
  alignas(16) bf16_t t[8];
  *(uint4*)t = *(const uint4*)pz;
#pragma unroll
  for (int i = 0; i < 8; ++i) v[i] += bf2f(t[i]);
}

// x = X + sum_{z<NZ} P[z] (bf16 partials); write X; y = LN(x).
// 256 thr = 4 waves = 4 rows/block.
template<int NZ>
__global__ void ln_sumN_kernel(float* __restrict__ X,
                               const bf16_t* __restrict__ P,
                               const float* __restrict__ gamma,
                               const float* __restrict__ beta,
                               bf16_t* __restrict__ Y)
{
  const int row  = blockIdx.x * 4 + (threadIdx.x >> 6);
  const int lane = threadIdx.x & 63;
  const int c0 = lane * 8;
  float* xr = X + (size_t)row * D_;
  float v[8];
  *(float4*)&v[0] = *(const float4*)&xr[c0];
  *(float4*)&v[4] = *(const float4*)&xr[c0 + 4];
#pragma unroll
  for (int z = 0; z < NZ; ++z)
    fold_p(v, P + (size_t)z * B_ * D_ + (size_t)row * D_ + c0);
  *(float4*)&xr[c0]     = *(const float4*)&v[0];
  *(float4*)&xr[c0 + 4] = *(const float4*)&v[4];
  ln_store(v, gamma, beta, Y + (size_t)row * D_, lane);
}

// Step boundary: h = X (+ P0..P3 if P != null); head logits of step t-1 from
// h (if out); x = emb_a + emb_b + h -> X; y = LN1_0(x). 4 rows/block.
__global__ void add_ln_kernel(const int* __restrict__ a_seq,
                              const int* __restrict__ b_seq,
                              const float* __restrict__ bit_emb,
                              const float* __restrict__ hsrc, int hstride,
                              const bf16_t* __restrict__ P,
                              float* __restrict__ X,
                              const float* __restrict__ gamma,
                              const float* __restrict__ beta,
                              bf16_t* __restrict__ Y, int t,
                              const float* __restrict__ hw,
                              const float* __restrict__ hb,
                              float* __restrict__ out)
{
  const int row  = blockIdx.x * 4 + (threadIdx.x >> 6);
  const int lane = threadIdx.x & 63;
  const int ai = a_seq[row * S_ + t];
  const int bi = b_seq[row * S_ + t];
  const int c0 = lane * 8;
  float* xr = X + (size_t)row * D_;
  const float* pr = hsrc + (size_t)row * hstride + c0;
  float ea[8], eb[8], p[8], v[8];
  *(float4*)&ea[0] = *(const float4*)&bit_emb[ai * D_ + c0];
  *(float4*)&ea[4] = *(const float4*)&bit_emb[ai * D_ + c0 + 4];
  *(float4*)&eb[0] = *(const float4*)&bit_emb[bi * D_ + c0];
  *(float4*)&eb[4] = *(const float4*)&bit_emb[bi * D_ + c0 + 4];
  *(float4*)&p[0]  = *(const float4*)&pr[0];
  *(float4*)&p[4]  = *(const float4*)&pr[4];

  if (P != nullptr) {  // fold split-K partials of previous step's g3
#pragma unroll
    for (int z = 0; z < 4; ++z)
      fold_p(p, P + (size_t)z * B_ * D_ + (size_t)row * D_ + c0);
  }

  if (out != nullptr) {  // head for step t-1 from h (= p[])
    float w[16];
#pragma unroll
    for (int i = 0; i < 4; ++i)
      *(float4*)&w[i * 4] = *(const float4*)&hw[lane * 16 + i * 4];
    float s0 = 0.f, s1 = 0.f;
#pragma unroll
    for (int i = 0; i < 8; ++i) { s0 += p[i] * w[2 * i]; s1 += p[i] * w[2 * i + 1]; }
#pragma unroll
    for (int o = 32; o; o >>= 1) { s0 += __shfl_xor(s0, o); s1 += __shfl_xor(s1, o); }
    if (lane == 0) {
      float* po = out + (size_t)row * (S_ * 2) + (t - 1) * 2;
      po[0] = s0 + hb[0];
      po[1] = s1 + hb[1];
    }
  }

#pragma unroll
  for (int i = 0; i < 8; ++i) v[i] = ea[i] + eb[i] + p[i];
  *(float4*)&xr[c0]     = *(const float4*)&v[0];
  *(float4*)&xr[c0 + 4] = *(const float4*)&v[4];
  ln_store(v, gamma, beta, Y + (size_t)row * D_, lane);
}

// Final head: h = X + P0..P3; logits[row, S-1, :] = h @ head_w + head_b.
__global__ void head_kernel(const float* __restrict__ X,
                            const bf16_t* __restrict__ P,
                            const float* __restrict__ hw,
                            const float* __restrict__ hb,
                            float* __restrict__ out, int t)
{
  const int row  = blockIdx.x * 4 + (threadIdx.x >> 6);
  const int lane = threadIdx.x & 63;
  const float* xr = X + (size_t)row * D_;
  const int c0 = lane * 8;
  float v[8];
  *(float4*)&v[0] = *(const float4*)&xr[c0];
  *(float4*)&v[4] = *(const float4*)&xr[c0 + 4];
#pragma unroll
  for (int z = 0; z < 4; ++z)
    fold_p(v, P + (size_t)z * B_ * D_ + (size_t)row * D_ + c0);
  float w[16];
#pragma unroll
  for (int i = 0; i < 4; ++i)
    *(float4*)&w[i * 4] = *(const float4*)&hw[lane * 16 + i * 4];
  float s0 = 0.f, s1 = 0.f;
#pragma unroll
  for (int i = 0; i < 8; ++i) { s0 += v[i] * w[2 * i]; s1 += v[i] * w[2 * i + 1]; }
#pragma unroll
  for (int o = 32; o; o >>= 1) { s0 += __shfl_xor(s0, o); s1 += __shfl_xor(s1, o); }
  if (lane == 0) {
    float* po = out + (size_t)row * (S_ * 2) + t * 2;
    po[0] = s0 + hb[0];
    po[1] = s1 + hb[1];
  }
}

// ---------------------------------------------------------------------------
// Prep kernels (run every launch; graph-safe)
// ---------------------------------------------------------------------------
__global__ void prep_wc(const float* __restrict__ qkv_w,
                        const float* __restrict__ out_w,
                        float* __restrict__ wc)
{
  const int n = blockIdx.x * 256 + threadIdx.x;
  const int k = blockIdx.y;
  const int l = blockIdx.z;
  const float* qrow = qkv_w + ((size_t)l * D_ + k) * (3 * D_) + 2 * D_;
  const float* ow   = out_w + (size_t)l * D_ * D_;
  float acc = 0.f;
  for (int j = 0; j < D_; ++j) acc += qrow[j] * ow[(size_t)j * D_ + n];
  wc[((size_t)l * D_ + k) * D_ + n] = acc;
}

__global__ void prep_bc(const float* __restrict__ qkv_b,
                        const float* __restrict__ out_w,
                        const float* __restrict__ out_b,
                        float* __restrict__ bc)
{
  const int l = blockIdx.x;
  const int n = threadIdx.x;
  const float* qb = qkv_b + (size_t)l * (3 * D_) + 2 * D_;
  const float* ow = out_w + (size_t)l * D_ * D_;
  float acc = out_b[(size_t)l * D_ + n];
  for (int j = 0; j < D_; ++j) acc += qb[j] * ow[(size_t)j * D_ + n];
  bc[(size_t)l * D_ + n] = acc;
}

// dst(C,R) bf16 = transpose(src(R,C) fp32), per-layer via blockIdx.z
__global__ void transpose_conv(const float* __restrict__ src,
                               bf16_t* __restrict__ dst, int R, int C)
{
  __shared__ float tile[32][33];
  const int l = blockIdx.z;
  const float* s = src + (size_t)l * R * C;
  bf16_t* d = dst + (size_t)l * R * C;
  const int c0 = blockIdx.x * 32, r0 = blockIdx.y * 32;
  const int tx = threadIdx.x, ty = threadIdx.y;
  tile[ty][tx] = s[(size_t)(r0 + ty) * C + (c0 + tx)];
  __syncthreads();
  d[(size_t)(c0 + ty) * R + (r0 + tx)] = __float2bfloat16(tile[tx][ty]);
}

// ---------------------------------------------------------------------------
extern "C" void kernel_launch(void* const* d_in, const int* in_sizes, int n_in,
                              void* d_out, int out_size, void* d_ws, size_t ws_size,
                              hipStream_t stream)
{
  const int*   a_seq     = (const int*)  d_in[0];
  const int*   b_seq     = (const int*)  d_in[1];
  const float* bit_emb   = (const float*)d_in[2];
  const float* start     = (const float*)d_in[3];
  const float* ln1_g     = (const float*)d_in[4];
  const float* ln1_b     = (const float*)d_in[5];
  const float* qkv_w     = (const float*)d_in[6];
  const float* qkv_b     = (const float*)d_in[7];
  const float* out_w     = (const float*)d_in[8];
  const float* out_b     = (const float*)d_in[9];
  const float* ln2_g     = (const float*)d_in[10];
  const float* ln2_b     = (const float*)d_in[11];
  const float* ff1_w     = (const float*)d_in[12];
  const float* ff1_b     = (const float*)d_in[13];
  const float* ff2_w     = (const float*)d_in[14];
  const float* ff2_b     = (const float*)d_in[15];
  const float* head_w    = (const float*)d_in[16];
  const float* head_b    = (const float*)d_in[17];
  float* out = (float*)d_out;

  // workspace layout
  char* ws = (char*)d_ws;
  float*  X     = (float*) ws; ws += (size_t)B_ * D_ * 4;              // 8 MB
  bf16_t* Y     = (bf16_t*)ws; ws += (size_t)B_ * D_ * 2;              // 4 MB
  bf16_t* U     = (bf16_t*)ws; ws += (size_t)B_ * 4 * D_ * 2;          // 16 MB
  bf16_t* WCT   = (bf16_t*)ws; ws += (size_t)DEPTH_ * D_ * D_ * 2;     // 2 MB
  bf16_t* FF1T  = (bf16_t*)ws; ws += (size_t)DEPTH_ * D_ * 4 * D_ * 2; // 8 MB
  bf16_t* FF2T  = (bf16_t*)ws; ws += (size_t)DEPTH_ * 4 * D_ * D_ * 2; // 8 MB
  float*  BC    = (float*) ws; ws += (size_t)DEPTH_ * D_ * 4;          // 8 KB
  float*  WCTMP = (float*) ws; ws += (size_t)DEPTH_ * D_ * D_ * 4;     // 4 MB
  bf16_t* PSPL  = (bf16_t*)ws; ws += (size_t)4 * B_ * D_ * 2;          // 16 MB g3 split-K partials
  bf16_t* P1    = (bf16_t*)ws; ws += (size_t)B_ * D_ * 2;              // 4 MB g1 partial

  // ---- weight prep (per launch, identical every call) ----
  prep_wc<<<dim3(2, 512, 4), 256, 0, stream>>>(qkv_w, out_w, WCTMP);
  prep_bc<<<4, 512, 0, stream>>>(qkv_b, out_w, out_b, BC);
  transpose_conv<<<dim3(16, 16, 4),  dim3(32, 32), 0, stream>>>(WCTMP, WCT, 512, 512);
  transpose_conv<<<dim3(64, 16, 4),  dim3(32, 32), 0, stream>>>(ff1_w, FF1T, 512, 2048);
  transpose_conv<<<dim3(16, 64, 4),  dim3(32, 32), 0, stream>>>(ff2_w, FF2T, 2048, 512);

  // ---- recurrent steps ----
  for (int t = 0; t < S_; ++t) {
    if (t == 0)
      add_ln_kernel<<<B_ / 4, 256, 0, stream>>>(a_seq, b_seq, bit_emb, start, 0,
                                                nullptr, X, ln1_g, ln1_b, Y, t,
                                                head_w, head_b, nullptr);
    else
      add_ln_kernel<<<B_ / 4, 256, 0, stream>>>(a_seq, b_seq, bit_emb, X, D_,
                                                PSPL, X, ln1_g, ln1_b, Y, t,
                                                head_w, head_b, out);
    for (int l = 0; l < DEPTH_; ++l) {
      // P1 = bf16(y @ Wc[l] + bc[l])   (64x64, BK=128 -> 4 iters, 512 blocks)
      gemm_bf16<64, 64, 128, 2, 1><<<dim3(64, 8), 256, 0, stream>>>(
          Y, WCT + (size_t)l * D_ * D_, BC + (size_t)l * D_, nullptr, P1,
          B_, D_, D_);
      // x += P1 ; y = LN2(x)
      ln_sumN_kernel<1><<<B_ / 4, 256, 0, stream>>>(X, P1,
                                                    ln2_g + (size_t)l * D_,
                                                    ln2_b + (size_t)l * D_, Y);
      // u = relu(y @ ff1[l] + b1)  (128x128, BK=128 -> 4 iters, 512 blocks)
      gemm_bf16<128, 128, 128, 1, 1><<<dim3(32, 16), 256, 0, stream>>>(
          Y, FF1T + (size_t)l * D_ * 4 * D_, ff1_b + (size_t)l * 4 * D_, nullptr, U,
          B_, 4 * D_, D_);
      // P[z] = bf16(u @ ff2[l] (+b2 in z=0))  (128x128, split-K=4, BK=128 ->
      //        4 iters/block, 512 blocks, plain bf16 stores)
      gemm_bf16<128, 128, 128, 2, 4><<<dim3(32, 4, 4), 256, 0, stream>>>(
          U, FF2T + (size_t)l * 4 * D_ * D_, ff2_b + (size_t)l * D_, nullptr, PSPL,
          B_, D_, 4 * D_);
      // x += P0..P3 ; y = LN1[l+1](x)
      if (l < DEPTH_ - 1)
        ln_sumN_kernel<4><<<B_ / 4, 256, 0, stream>>>(X, PSPL,
                                                      ln1_g + (size_t)(l + 1) * D_,
                                                      ln1_b + (size_t)(l + 1) * D_, Y);
      // at l==3 the partials are folded by the next add_ln / final head
    }
  }
  head_kernel<<<B_ / 4, 256, 0, stream>>>(X, PSPL, head_w, head_b, out, S_ - 1);
}

// Round 10
// 15087.865 us; speedup vs baseline: 1.2378x; 1.2378x over previous
//
#include <hip/hip_runtime.h>
#include <hip/hip_bf16.h>
#include <stdint.h>
#include <stddef.h>

// Problem constants
#define B_ 4096
#define S_ 64
#define D_ 512
#define DEPTH_ 4

// ---------------------------------------------------------------------------
// FINAL CONFIG (R10) — best-known design, locked:
//  * algebra: qkv reduced to v-only; (Wv@Wo) precomposed -> Wc (exact)
//  * GEMMs: m97-style 2-barrier K-loop, BK=64 (BK=128 regresses: R9/m132),
//    global_load_lds width=16 staging, mfma 16x16x32 bf16, fp32 acc
//  * grids always >=512 blocks (2+ blocks/CU co-residency; 256-block grids
//    regress ~20-30%: R2/R3/R5 evidence)
//  * g3 split-K=4 with PLAIN bf16 partial stores (atomics poison the
//    epilogue: R2; fp32 partials waste BW: R7); reduce folded into the
//    next LN-ish kernel which reads X anyway
//  * g1 stores bf16 partial (no RMW); ln_sum1 folds it (R8)
//  * glue kernels: 4 rows/block, one wave per row, bf16x8 vector IO
//  * NO cross-block sync of any kind (R4: fences+counters = catastrophic)
//  * NO XCD swizzle (R8: neutral; removed to save VALU)
// ---------------------------------------------------------------------------

typedef __attribute__((ext_vector_type(8))) __bf16 bf16x8;
typedef __attribute__((ext_vector_type(4))) float f32x4;
typedef __hip_bfloat16 bf16_t;

__device__ __forceinline__ void async_copy16(const void* g, void* lds) {
  __builtin_amdgcn_global_load_lds(
      (const __attribute__((address_space(1))) void*)g,
      (__attribute__((address_space(3))) void*)lds, 16, 0, 0);
}

__device__ __forceinline__ float bf2f(bf16_t h) { return __bfloat162float(h); }

// ---------------------------------------------------------------------------
// GEMM: C(M,N) = A(M,K) @ Bt(N,K)^T  (+bias)
//   EPI 1: O[row*N+col]  = bf16(relu(acc+b))   (SPLITK==1)
//   EPI 2: O[z*M*N + row*N+col] = bf16(acc (+bias if z==0))
// ---------------------------------------------------------------------------
template<int TM, int TN, int EPI, int SPLITK>
__launch_bounds__(256)
__global__ void gemm_bf16(const bf16_t* __restrict__ A,
                          const bf16_t* __restrict__ Bt,
                          const float* __restrict__ bias,
                          bf16_t* __restrict__ O,
                          int M, int N, int K)
{
  constexpr int BK  = 64;
  constexpr int WM  = TM / 2, WN = TN / 2;
  constexpr int NMI = WM / 16, NNI = WN / 16;
  constexpr int CA  = TM / 8, CB = TN / 8;   // 1KB chunks (8 rows of 128B)

  __shared__ __align__(16) bf16_t sA[TM * BK];
  __shared__ __align__(16) bf16_t sB[TN * BK];

  const int tid  = threadIdx.x;
  const int lane = tid & 63;
  const int wave = tid >> 6;
  const int wm   = wave & 1;
  const int wn   = wave >> 1;
  const int m0   = blockIdx.x * TM;
  const int n0   = blockIdx.y * TN;
  const int KS   = K / SPLITK;
  const int kbeg = blockIdx.z * KS;

  const int lr = lane >> 3;        // row within 1KB chunk (8 rows)
  const int lc = (lane & 7) * 8;   // bf16 col within row

  f32x4 acc[NMI][NNI];
#pragma unroll
  for (int mi = 0; mi < NMI; ++mi)
#pragma unroll
    for (int ni = 0; ni < NNI; ++ni)
      acc[mi][ni] = (f32x4){0.f, 0.f, 0.f, 0.f};

  for (int k0 = kbeg; k0 < kbeg + KS; k0 += BK) {
#pragma unroll
    for (int c = wave; c < CA; c += 4) {
      const bf16_t* g = A + (size_t)(m0 + c * 8 + lr) * K + (k0 + lc);
      async_copy16(g, (char*)sA + c * 1024);
    }
#pragma unroll
    for (int c = wave; c < CB; c += 4) {
      const bf16_t* g = Bt + (size_t)(n0 + c * 8 + lr) * K + (k0 + lc);
      async_copy16(g, (char*)sB + c * 1024);
    }
    __syncthreads();   // drains vmcnt(0) -> LDS ready

#pragma unroll
    for (int kk = 0; kk < BK; kk += 32) {
      bf16x8 af[NMI], bfv[NNI];
#pragma unroll
      for (int mi = 0; mi < NMI; ++mi)
        af[mi] = *(const bf16x8*)&sA[(wm * WM + mi * 16 + (lane & 15)) * BK + kk + (lane >> 4) * 8];
#pragma unroll
      for (int ni = 0; ni < NNI; ++ni)
        bfv[ni] = *(const bf16x8*)&sB[(wn * WN + ni * 16 + (lane & 15)) * BK + kk + (lane >> 4) * 8];
#pragma unroll
      for (int mi = 0; mi < NMI; ++mi)
#pragma unroll
        for (int ni = 0; ni < NNI; ++ni)
          acc[mi][ni] = __builtin_amdgcn_mfma_f32_16x16x32_bf16(af[mi], bfv[ni], acc[mi][ni], 0, 0, 0);
    }
    __syncthreads();   // protect LDS before next stage
  }

  // epilogue. C/D layout (verified m89/m91): col = lane&15, row = (lane>>4)*4 + r
#pragma unroll
  for (int mi = 0; mi < NMI; ++mi) {
#pragma unroll
    for (int ni = 0; ni < NNI; ++ni) {
      const int col  = n0 + wn * WN + ni * 16 + (lane & 15);
      const int row0 = m0 + wm * WM + mi * 16 + ((lane >> 4) << 2);
      const float bv = (SPLITK == 1 || blockIdx.z == 0) ? bias[col] : 0.f;
#pragma unroll
      for (int r = 0; r < 4; ++r) {
        const float v = acc[mi][ni][r] + bv;
        const size_t idx = (size_t)(row0 + r) * N + col;
        if constexpr (EPI == 1) {
          O[idx] = __float2bfloat16(v > 0.f ? v : 0.f);
        } else {
          O[(size_t)blockIdx.z * M * N + idx] = __float2bfloat16(v);
        }
      }
    }
  }
}

// ---------------------------------------------------------------------------
// LayerNorm row helper: v[8] per lane (64 lanes x 8 = 512), write bf16 row
// ---------------------------------------------------------------------------
__device__ __forceinline__ void ln_store(const float v[8],
                                         const float* __restrict__ gamma,
                                         const float* __restrict__ beta,
                                         bf16_t* __restrict__ yrow, int lane)
{
  float s = 0.f, ss = 0.f;
#pragma unroll
  for (int i = 0; i < 8; ++i) { s += v[i]; ss += v[i] * v[i]; }
#pragma unroll
  for (int o = 32; o; o >>= 1) { s += __shfl_xor(s, o); ss += __shfl_xor(ss, o); }
  const float m   = s * (1.f / D_);
  const float inv = rsqrtf(ss * (1.f / D_) - m * m + 1e-5f);
  const int c0 = lane * 8;
  float g[8], b[8];
  *(float4*)&g[0] = *(const float4*)&gamma[c0];
  *(float4*)&g[4] = *(const float4*)&gamma[c0 + 4];
  *(float4*)&b[0] = *(const float4*)&beta[c0];
  *(float4*)&b[4] = *(const float4*)&beta[c0 + 4];
  alignas(16) bf16_t o8[8];
#pragma unroll
  for (int i = 0; i < 8; ++i)
    o8[i] = __float2bfloat16((v[i] - m) * inv * g[i] + b[i]);
  *(uint4*)&yrow[c0] = *(const uint4*)o8;
}

// fold bf16 partial row-chunk into v[8]
__device__ __forceinline__ void fold_p(float v[8], const bf16_t* pz)
{
  alignas(16) bf16_t t[8];
  *(uint4*)t = *(const uint4*)pz;
#pragma unroll
  for (int i = 0; i < 8; ++i) v[i] += bf2f(t[i]);
}

// x = X + sum_{z<NZ} P[z] (bf16 partials); write X; y = LN(x).
// 256 thr = 4 waves = 4 rows/block.
template<int NZ>
__global__ void ln_sumN_kernel(float* __restrict__ X,
                               const bf16_t* __restrict__ P,
                               const float* __restrict__ gamma,
                               const float* __restrict__ beta,
                               bf16_t* __restrict__ Y)
{
  const int row  = blockIdx.x * 4 + (threadIdx.x >> 6);
  const int lane = threadIdx.x & 63;
  const int c0 = lane * 8;
  float* xr = X + (size_t)row * D_;
  float v[8];
  *(float4*)&v[0] = *(const float4*)&xr[c0];
  *(float4*)&v[4] = *(const float4*)&xr[c0 + 4];
#pragma unroll
  for (int z = 0; z < NZ; ++z)
    fold_p(v, P + (size_t)z * B_ * D_ + (size_t)row * D_ + c0);
  *(float4*)&xr[c0]     = *(const float4*)&v[0];
  *(float4*)&xr[c0 + 4] = *(const float4*)&v[4];
  ln_store(v, gamma, beta, Y + (size_t)row * D_, lane);
}

// Step boundary: h = X (+ P0..P3 if P != null); head logits of step t-1 from
// h (if out); x = emb_a + emb_b + h -> X; y = LN1_0(x). 4 rows/block.
__global__ void add_ln_kernel(const int* __restrict__ a_seq,
                              const int* __restrict__ b_seq,
                              const float* __restrict__ bit_emb,
                              const float* __restrict__ hsrc, int hstride,
                              const bf16_t* __restrict__ P,
                              float* __restrict__ X,
                              const float* __restrict__ gamma,
                              const float* __restrict__ beta,
                              bf16_t* __restrict__ Y, int t,
                              const float* __restrict__ hw,
                              const float* __restrict__ hb,
                              float* __restrict__ out)
{
  const int row  = blockIdx.x * 4 + (threadIdx.x >> 6);
  const int lane = threadIdx.x & 63;
  const int ai = a_seq[row * S_ + t];
  const int bi = b_seq[row * S_ + t];
  const int c0 = lane * 8;
  float* xr = X + (size_t)row * D_;
  const float* pr = hsrc + (size_t)row * hstride + c0;
  float ea[8], eb[8], p[8], v[8];
  *(float4*)&ea[0] = *(const float4*)&bit_emb[ai * D_ + c0];
  *(float4*)&ea[4] = *(const float4*)&bit_emb[ai * D_ + c0 + 4];
  *(float4*)&eb[0] = *(const float4*)&bit_emb[bi * D_ + c0];
  *(float4*)&eb[4] = *(const float4*)&bit_emb[bi * D_ + c0 + 4];
  *(float4*)&p[0]  = *(const float4*)&pr[0];
  *(float4*)&p[4]  = *(const float4*)&pr[4];

  if (P != nullptr) {  // fold split-K partials of previous step's g3
#pragma unroll
    for (int z = 0; z < 4; ++z)
      fold_p(p, P + (size_t)z * B_ * D_ + (size_t)row * D_ + c0);
  }

  if (out != nullptr) {  // head for step t-1 from h (= p[])
    float w[16];
#pragma unroll
    for (int i = 0; i < 4; ++i)
      *(float4*)&w[i * 4] = *(const float4*)&hw[lane * 16 + i * 4];
    float s0 = 0.f, s1 = 0.f;
#pragma unroll
    for (int i = 0; i < 8; ++i) { s0 += p[i] * w[2 * i]; s1 += p[i] * w[2 * i + 1]; }
#pragma unroll
    for (int o = 32; o; o >>= 1) { s0 += __shfl_xor(s0, o); s1 += __shfl_xor(s1, o); }
    if (lane == 0) {
      float* po = out + (size_t)row * (S_ * 2) + (t - 1) * 2;
      po[0] = s0 + hb[0];
      po[1] = s1 + hb[1];
    }
  }

#pragma unroll
  for (int i = 0; i < 8; ++i) v[i] = ea[i] + eb[i] + p[i];
  *(float4*)&xr[c0]     = *(const float4*)&v[0];
  *(float4*)&xr[c0 + 4] = *(const float4*)&v[4];
  ln_store(v, gamma, beta, Y + (size_t)row * D_, lane);
}

// Final head: h = X + P0..P3; logits[row, S-1, :] = h @ head_w + head_b.
__global__ void head_kernel(const float* __restrict__ X,
                            const bf16_t* __restrict__ P,
                            const float* __restrict__ hw,
                            const float* __restrict__ hb,
                            float* __restrict__ out, int t)
{
  const int row  = blockIdx.x * 4 + (threadIdx.x >> 6);
  const int lane = threadIdx.x & 63;
  const float* xr = X + (size_t)row * D_;
  const int c0 = lane * 8;
  float v[8];
  *(float4*)&v[0] = *(const float4*)&xr[c0];
  *(float4*)&v[4] = *(const float4*)&xr[c0 + 4];
#pragma unroll
  for (int z = 0; z < 4; ++z)
    fold_p(v, P + (size_t)z * B_ * D_ + (size_t)row * D_ + c0);
  float w[16];
#pragma unroll
  for (int i = 0; i < 4; ++i)
    *(float4*)&w[i * 4] = *(const float4*)&hw[lane * 16 + i * 4];
  float s0 = 0.f, s1 = 0.f;
#pragma unroll
  for (int i = 0; i < 8; ++i) { s0 += v[i] * w[2 * i]; s1 += v[i] * w[2 * i + 1]; }
#pragma unroll
  for (int o = 32; o; o >>= 1) { s0 += __shfl_xor(s0, o); s1 += __shfl_xor(s1, o); }
  if (lane == 0) {
    float* po = out + (size_t)row * (S_ * 2) + t * 2;
    po[0] = s0 + hb[0];
    po[1] = s1 + hb[1];
  }
}

// ---------------------------------------------------------------------------
// Prep kernels (run every launch; graph-safe)
// ---------------------------------------------------------------------------
__global__ void prep_wc(const float* __restrict__ qkv_w,
                        const float* __restrict__ out_w,
                        float* __restrict__ wc)
{
  const int n = blockIdx.x * 256 + threadIdx.x;
  const int k = blockIdx.y;
  const int l = blockIdx.z;
  const float* qrow = qkv_w + ((size_t)l * D_ + k) * (3 * D_) + 2 * D_;
  const float* ow   = out_w + (size_t)l * D_ * D_;
  float acc = 0.f;
  for (int j = 0; j < D_; ++j) acc += qrow[j] * ow[(size_t)j * D_ + n];
  wc[((size_t)l * D_ + k) * D_ + n] = acc;
}

__global__ void prep_bc(const float* __restrict__ qkv_b,
                        const float* __restrict__ out_w,
                        const float* __restrict__ out_b,
                        float* __restrict__ bc)
{
  const int l = blockIdx.x;
  const int n = threadIdx.x;
  const float* qb = qkv_b + (size_t)l * (3 * D_) + 2 * D_;
  const float* ow = out_w + (size_t)l * D_ * D_;
  float acc = out_b[(size_t)l * D_ + n];
  for (int j = 0; j < D_; ++j) acc += qb[j] * ow[(size_t)j * D_ + n];
  bc[(size_t)l * D_ + n] = acc;
}

// dst(C,R) bf16 = transpose(src(R,C) fp32), per-layer via blockIdx.z
__global__ void transpose_conv(const float* __restrict__ src,
                               bf16_t* __restrict__ dst, int R, int C)
{
  __shared__ float tile[32][33];
  const int l = blockIdx.z;
  const float* s = src + (size_t)l * R * C;
  bf16_t* d = dst + (size_t)l * R * C;
  const int c0 = blockIdx.x * 32, r0 = blockIdx.y * 32;
  const int tx = threadIdx.x, ty = threadIdx.y;
  tile[ty][tx] = s[(size_t)(r0 + ty) * C + (c0 + tx)];
  __syncthreads();
  d[(size_t)(c0 + ty) * R + (r0 + tx)] = __float2bfloat16(tile[tx][ty]);
}

// ---------------------------------------------------------------------------
extern "C" void kernel_launch(void* const* d_in, const int* in_sizes, int n_in,
                              void* d_out, int out_size, void* d_ws, size_t ws_size,
                              hipStream_t stream)
{
  const int*   a_seq     = (const int*)  d_in[0];
  const int*   b_seq     = (const int*)  d_in[1];
  const float* bit_emb   = (const float*)d_in[2];
  const float* start     = (const float*)d_in[3];
  const float* ln1_g     = (const float*)d_in[4];
  const float* ln1_b     = (const float*)d_in[5];
  const float* qkv_w     = (const float*)d_in[6];
  const float* qkv_b     = (const float*)d_in[7];
  const float* out_w     = (const float*)d_in[8];
  const float* out_b     = (const float*)d_in[9];
  const float* ln2_g     = (const float*)d_in[10];
  const float* ln2_b     = (const float*)d_in[11];
  const float* ff1_w     = (const float*)d_in[12];
  const float* ff1_b     = (const float*)d_in[13];
  const float* ff2_w     = (const float*)d_in[14];
  const float* ff2_b     = (const float*)d_in[15];
  const float* head_w    = (const float*)d_in[16];
  const float* head_b    = (const float*)d_in[17];
  float* out = (float*)d_out;

  // workspace layout
  char* ws = (char*)d_ws;
  float*  X     = (float*) ws; ws += (size_t)B_ * D_ * 4;              // 8 MB
  bf16_t* Y     = (bf16_t*)ws; ws += (size_t)B_ * D_ * 2;              // 4 MB
  bf16_t* U     = (bf16_t*)ws; ws += (size_t)B_ * 4 * D_ * 2;          // 16 MB
  bf16_t* WCT   = (bf16_t*)ws; ws += (size_t)DEPTH_ * D_ * D_ * 2;     // 2 MB
  bf16_t* FF1T  = (bf16_t*)ws; ws += (size_t)DEPTH_ * D_ * 4 * D_ * 2; // 8 MB
  bf16_t* FF2T  = (bf16_t*)ws; ws += (size_t)DEPTH_ * 4 * D_ * D_ * 2; // 8 MB
  float*  BC    = (float*) ws; ws += (size_t)DEPTH_ * D_ * 4;          // 8 KB
  float*  WCTMP = (float*) ws; ws += (size_t)DEPTH_ * D_ * D_ * 4;     // 4 MB
  bf16_t* PSPL  = (bf16_t*)ws; ws += (size_t)4 * B_ * D_ * 2;          // 16 MB g3 split-K partials
  bf16_t* P1    = (bf16_t*)ws; ws += (size_t)B_ * D_ * 2;              // 4 MB g1 partial

  // ---- weight prep (per launch, identical every call) ----
  prep_wc<<<dim3(2, 512, 4), 256, 0, stream>>>(qkv_w, out_w, WCTMP);
  prep_bc<<<4, 512, 0, stream>>>(qkv_b, out_w, out_b, BC);
  transpose_conv<<<dim3(16, 16, 4),  dim3(32, 32), 0, stream>>>(WCTMP, WCT, 512, 512);
  transpose_conv<<<dim3(64, 16, 4),  dim3(32, 32), 0, stream>>>(ff1_w, FF1T, 512, 2048);
  transpose_conv<<<dim3(16, 64, 4),  dim3(32, 32), 0, stream>>>(ff2_w, FF2T, 2048, 512);

  // ---- recurrent steps ----
  for (int t = 0; t < S_; ++t) {
    if (t == 0)
      add_ln_kernel<<<B_ / 4, 256, 0, stream>>>(a_seq, b_seq, bit_emb, start, 0,
                                                nullptr, X, ln1_g, ln1_b, Y, t,
                                                head_w, head_b, nullptr);
    else
      add_ln_kernel<<<B_ / 4, 256, 0, stream>>>(a_seq, b_seq, bit_emb, X, D_,
                                                PSPL, X, ln1_g, ln1_b, Y, t,
                                                head_w, head_b, out);
    for (int l = 0; l < DEPTH_; ++l) {
      // P1 = bf16(y @ Wc[l] + bc[l])   (64x64, BK=64, 512 blocks)
      gemm_bf16<64, 64, 2, 1><<<dim3(64, 8), 256, 0, stream>>>(
          Y, WCT + (size_t)l * D_ * D_, BC + (size_t)l * D_, P1,
          B_, D_, D_);
      // x += P1 ; y = LN2(x)
      ln_sumN_kernel<1><<<B_ / 4, 256, 0, stream>>>(X, P1,
                                                    ln2_g + (size_t)l * D_,
                                                    ln2_b + (size_t)l * D_, Y);
      // u = relu(y @ ff1[l] + b1)  (128x128, BK=64, 512 blocks)
      gemm_bf16<128, 128, 1, 1><<<dim3(32, 16), 256, 0, stream>>>(
          Y, FF1T + (size_t)l * D_ * 4 * D_, ff1_b + (size_t)l * 4 * D_, U,
          B_, 4 * D_, D_);
      // P[z] = bf16(u @ ff2[l] (+b2 in z=0))  (128x128, split-K=4, BK=64,
      //        512 blocks, plain bf16 stores, 8 BK-iters/block)
      gemm_bf16<128, 128, 2, 4><<<dim3(32, 4, 4), 256, 0, stream>>>(
          U, FF2T + (size_t)l * 4 * D_ * D_, ff2_b + (size_t)l * D_, PSPL,
          B_, D_, 4 * D_);
      // x += P0..P3 ; y = LN1[l+1](x)
      if (l < DEPTH_ - 1)
        ln_sumN_kernel<4><<<B_ / 4, 256, 0, stream>>>(X, PSPL,
                                                      ln1_g + (size_t)(l + 1) * D_,
                                                      ln1_b + (size_t)(l + 1) * D_, Y);
      // at l==3 the partials are folded by the next add_ln / final head
    }
  }
  head_kernel<<<B_ / 4, 256, 0, stream>>>(X, PSPL, head_w, head_b, out, S_ - 1);
}